// Round 2
// baseline (437.245 us; speedup 1.0000x reference)
//
#include <hip/hip_runtime.h>
#include <hip/hip_bf16.h>

typedef __attribute__((ext_vector_type(8))) short short8;
typedef __attribute__((ext_vector_type(4))) float f32x4;

#define L 4096
#define CCH 128
#define NH 4
#define HD 32
#define NSB 4  // 2 streams * 2 batches

static __device__ __forceinline__ unsigned short f2bf(float f) {
  unsigned int u = __float_as_uint(f);
  u += 0x7FFFu + ((u >> 16) & 1u);
  return (unsigned short)(u >> 16);
}

// ---------------- GroupNorm: 64 blocks (s*32 + b*16 + g), 256 thr ----------------
__global__ void __launch_bounds__(256) gn_kernel(
    const float* __restrict__ xA, const float* __restrict__ xB,
    const float* __restrict__ gwA, const float* __restrict__ gbA,
    const float* __restrict__ gwB, const float* __restrict__ gbB,
    float* __restrict__ xn, unsigned short* __restrict__ xnT) {
  int bid = blockIdx.x;
  int g = bid & 15;
  int b = (bid >> 4) & 1;
  int s = bid >> 5;
  const float* x  = s ? xB : xA;
  const float* gw = s ? gwB : gwA;
  const float* gb = s ? gbB : gbA;
  int sb = s * 2 + b;
  const float* xb = x + (size_t)b * CCH * L + (size_t)g * 8 * L;
  int t = threadIdx.x;
  float sum = 0.f, sq = 0.f;
  for (int e = t; e < 8 * L; e += 256) {
    float v = xb[e];
    sum += v; sq += v * v;
  }
  #pragma unroll
  for (int off = 32; off; off >>= 1) {
    sum += __shfl_down(sum, off);
    sq  += __shfl_down(sq, off);
  }
  __shared__ float red[2][4];
  __shared__ float stat[2];
  int w = t >> 6, lane = t & 63;
  if (lane == 0) { red[0][w] = sum; red[1][w] = sq; }
  __syncthreads();
  if (t == 0) {
    float S = red[0][0] + red[0][1] + red[0][2] + red[0][3];
    float Q = red[1][0] + red[1][1] + red[1][2] + red[1][3];
    float mu = S * (1.f / 32768.f);
    float var = Q * (1.f / 32768.f) - mu * mu;
    stat[0] = mu;
    stat[1] = rsqrtf(var + 1e-5f);
  }
  __syncthreads();
  float mu = stat[0], rs = stat[1];
  for (int e = t; e < 8 * L; e += 256) {
    int cl = e >> 12;
    int l  = e & (L - 1);
    int c  = g * 8 + cl;
    float v = (xb[e] - mu) * rs * gw[c] + gb[c];
    xn[((size_t)sb * CCH + c) * L + l] = v;
    xnT[((size_t)sb * L + l) * CCH + c] = f2bf(v);
  }
}

// ---------------- QKV GEMM: grid NSB*24*64, 256 thr (4 waves, one 16x16 tile each) --
// y[o][l] = sum_c w[o][c] * xn[c][l];  o in [0,384), per (s,b).
// Writes qT/kT as [sb][h][L][32] bf16, v as [sb][h][32][L] bf16.
__global__ void __launch_bounds__(256) qkv_kernel(
    const float* __restrict__ wA, const float* __restrict__ wB,
    const unsigned short* __restrict__ xnT,
    unsigned short* __restrict__ qT, unsigned short* __restrict__ kT,
    unsigned short* __restrict__ vv) {
  int bid = blockIdx.x;
  int nc = bid & 63;
  int mt = (bid >> 6) % 24;
  int sb = bid / (24 * 64);
  int s = sb >> 1;
  const float* wq = s ? wB : wA;
  int t = threadIdx.x;
  int w = t >> 6, lane = t & 63, ln = lane & 15, sub = lane >> 4;
  int obase = mt * 16;
  int lbase = nc * 64 + w * 16;
  const unsigned short* bbase = xnT + ((size_t)sb * L + lbase + ln) * CCH;
  const float* abase = wq + (size_t)(obase + ln) * CCH;
  f32x4 acc = {0.f, 0.f, 0.f, 0.f};
  #pragma unroll
  for (int kc = 0; kc < 4; ++kc) {
    int k0 = kc * 32 + sub * 8;
    const float* ap = abase + k0;
    short8 af;
    #pragma unroll
    for (int j = 0; j < 8; ++j) af[j] = (short)f2bf(ap[j]);
    short8 bfr = *(const short8*)(bbase + k0);
    acc = __builtin_amdgcn_mfma_f32_16x16x32_bf16(af, bfr, acc, 0, 0, 0);
  }
  int lcol = lbase + ln;
  #pragma unroll
  for (int r = 0; r < 4; ++r) {
    int o = obase + sub * 4 + r;
    int head = o / 96;
    int rem = o - head * 96;
    int part = rem >> 5;
    int dd = rem & 31;
    unsigned short val = f2bf(acc[r]);
    size_t bh = (size_t)sb * NH + head;
    if (part == 0)      qT[(bh * L + lcol) * HD + dd] = val;
    else if (part == 1) kT[(bh * L + lcol) * HD + dd] = val;
    else                vv[(bh * HD + dd) * L + lcol] = val;
  }
}

// ---------------- Flash attention: grid 2*2*4*64 = 1024 blocks, 256 thr -------------
// Output stream s uses queries of stream s^1 and K/V of stream s.
// lds_p regions are wave-private => NO __syncthreads() needed in the K-loop;
// wave-internal DS ordering (lgkmcnt) is sufficient.
__global__ void __launch_bounds__(256) flash_kernel(
    const unsigned short* __restrict__ qT, const unsigned short* __restrict__ kT,
    const unsigned short* __restrict__ vv, unsigned short* __restrict__ ao) {
  int bid = blockIdx.x;
  int qt = bid & 63;
  int h  = (bid >> 6) & 3;
  int b  = (bid >> 8) & 1;
  int s  = bid >> 9;
  size_t bh_kv = (size_t)((s * 2 + b) * NH + h);
  size_t bh_q  = (size_t)(((s ^ 1) * 2 + b) * NH + h);
  const unsigned short* qTb = qT + bh_q * L * HD;
  const unsigned short* kTb = kT + bh_kv * L * HD;
  const unsigned short* vb  = vv + bh_kv * HD * L;

  int t = threadIdx.x;
  int w = t >> 6, lane = t & 63, ln = lane & 15, sub = lane >> 4;
  int qbase = qt * 64 + w * 16;

  __shared__ unsigned short lds_p[4][16][32];

  // Q fragment, hoisted: A[m=qi][k=d] = qT[qbase+ln][sub*8 + j]
  short8 aq = *(const short8*)(qTb + (size_t)(qbase + ln) * HD + sub * 8);

  f32x4 acc0 = {0.f, 0.f, 0.f, 0.f}, acc1 = {0.f, 0.f, 0.f, 0.f};
  float m[4] = {-1e30f, -1e30f, -1e30f, -1e30f};
  float lsum[4] = {0.f, 0.f, 0.f, 0.f};
  const float scale = 0.08838834764831845f;  // 1/sqrt(128)

  for (int kt = 0; kt < L / 32; ++kt) {
    int kbase = kt * 32;
    // K fragments: B[k=d][n=ki] = kT[kbase+nh*16+ln][sub*8 + j]
    short8 bk0 = *(const short8*)(kTb + (size_t)(kbase + ln) * HD + sub * 8);
    short8 bk1 = *(const short8*)(kTb + (size_t)(kbase + 16 + ln) * HD + sub * 8);
    f32x4 zz = {0.f, 0.f, 0.f, 0.f};
    f32x4 s0 = __builtin_amdgcn_mfma_f32_16x16x32_bf16(aq, bk0, zz, 0, 0, 0);
    f32x4 s1 = __builtin_amdgcn_mfma_f32_16x16x32_bf16(aq, bk1, zz, 0, 0, 0);

    float p0[4], p1[4];
    #pragma unroll
    for (int r = 0; r < 4; ++r) {
      float a = s0[r] * scale;
      float c = s1[r] * scale;
      float mx = fmaxf(a, c);
      #pragma unroll
      for (int off = 1; off < 16; off <<= 1) mx = fmaxf(mx, __shfl_xor(mx, off));
      float newm = fmaxf(m[r], mx);
      float alpha = __expf(m[r] - newm);
      float pa = __expf(a - newm);
      float pc = __expf(c - newm);
      float rsum = pa + pc;
      #pragma unroll
      for (int off = 1; off < 16; off <<= 1) rsum += __shfl_xor(rsum, off);
      lsum[r] = lsum[r] * alpha + rsum;
      m[r] = newm;
      acc0[r] *= alpha;
      acc1[r] *= alpha;
      p0[r] = pa;
      p1[r] = pc;
    }
    // P tile to wave-private LDS, re-layout for PV A-fragment (no block barrier)
    #pragma unroll
    for (int r = 0; r < 4; ++r) {
      lds_p[w][sub * 4 + r][ln] = f2bf(p0[r]);
      lds_p[w][sub * 4 + r][16 + ln] = f2bf(p1[r]);
    }
    short8 pa_f = *(const short8*)(&lds_p[w][ln][sub * 8]);
    // V fragments: B[k=ki][n=d] = v[nh*16+ln][kbase + sub*8 + j]
    short8 bv0 = *(const short8*)(vb + (size_t)ln * L + kbase + sub * 8);
    short8 bv1 = *(const short8*)(vb + (size_t)(16 + ln) * L + kbase + sub * 8);
    acc0 = __builtin_amdgcn_mfma_f32_16x16x32_bf16(pa_f, bv0, acc0, 0, 0, 0);
    acc1 = __builtin_amdgcn_mfma_f32_16x16x32_bf16(pa_f, bv1, acc1, 0, 0, 0);
  }

  // epilogue: normalize, write attn_out as [sb][L][C] bf16 (c = h*32 + d)
  #pragma unroll
  for (int r = 0; r < 4; ++r) {
    float inv = 1.0f / lsum[r];
    int qrow = qbase + sub * 4 + r;
    size_t rowoff = ((size_t)(s * 2 + b) * L + qrow) * CCH + h * HD;
    ao[rowoff + ln] = f2bf(acc0[r] * inv);
    ao[rowoff + 16 + ln] = f2bf(acc1[r] * inv);
  }
}

// ---------------- Out-proj GEMM + bias + residual: grid NSB*8*64, 256 thr -----------
__global__ void __launch_bounds__(256) outproj_kernel(
    const float* __restrict__ woA, const float* __restrict__ boA,
    const float* __restrict__ woB, const float* __restrict__ boB,
    const unsigned short* __restrict__ ao, const float* __restrict__ xn,
    float* __restrict__ out) {
  int bid = blockIdx.x;
  int nc = bid & 63;
  int mt = (bid >> 6) & 7;
  int sb = bid >> 9;
  int s = sb >> 1;
  int b = sb & 1;
  const float* wo = s ? woB : woA;
  const float* bo = s ? boB : boA;
  int t = threadIdx.x;
  int w = t >> 6, lane = t & 63, ln = lane & 15, sub = lane >> 4;
  int obase = mt * 16;
  int lbase = nc * 64 + w * 16;
  const unsigned short* bbase = ao + ((size_t)sb * L + lbase + ln) * CCH;
  const float* abase = wo + (size_t)(obase + ln) * CCH;
  f32x4 acc = {0.f, 0.f, 0.f, 0.f};
  #pragma unroll
  for (int kc = 0; kc < 4; ++kc) {
    int k0 = kc * 32 + sub * 8;
    const float* ap = abase + k0;
    short8 af;
    #pragma unroll
    for (int j = 0; j < 8; ++j) af[j] = (short)f2bf(ap[j]);
    short8 bfr = *(const short8*)(bbase + k0);
    acc = __builtin_amdgcn_mfma_f32_16x16x32_bf16(af, bfr, acc, 0, 0, 0);
  }
  int lcol = lbase + ln;
  #pragma unroll
  for (int r = 0; r < 4; ++r) {
    int o = obase + sub * 4 + r;
    out[(size_t)s * (2 * CCH * L) + ((size_t)b * CCH + o) * L + lcol] =
        acc[r] + bo[o] + xn[((size_t)sb * CCH + o) * L + lcol];
  }
}

extern "C" void kernel_launch(void* const* d_in, const int* in_sizes, int n_in,
                              void* d_out, int out_size, void* d_ws, size_t ws_size,
                              hipStream_t stream) {
  (void)in_sizes; (void)n_in; (void)out_size; (void)ws_size;
  const float* xA  = (const float*)d_in[0];
  const float* xB  = (const float*)d_in[1];
  const float* gwA = (const float*)d_in[2];
  const float* gbA = (const float*)d_in[3];
  const float* gwB = (const float*)d_in[4];
  const float* gbB = (const float*)d_in[5];
  const float* wqA = (const float*)d_in[6];
  const float* wqB = (const float*)d_in[7];
  const float* woA = (const float*)d_in[8];
  const float* boA = (const float*)d_in[9];
  const float* woB = (const float*)d_in[10];
  const float* boB = (const float*)d_in[11];
  float* out = (float*)d_out;

  char* ws = (char*)d_ws;
  size_t off = 0;
  float* xn = (float*)(ws + off);            off += (size_t)NSB * CCH * L * sizeof(float); // 8 MB
  unsigned short* xnT = (unsigned short*)(ws + off); off += (size_t)NSB * L * CCH * 2;     // 4 MB
  unsigned short* qT  = (unsigned short*)(ws + off); off += (size_t)NSB * NH * L * HD * 2; // 4 MB
  unsigned short* kT  = (unsigned short*)(ws + off); off += (size_t)NSB * NH * L * HD * 2; // 4 MB
  unsigned short* vv  = (unsigned short*)(ws + off); off += (size_t)NSB * NH * HD * L * 2; // 4 MB
  unsigned short* ao  = (unsigned short*)(ws + off); off += (size_t)NSB * L * CCH * 2;     // 4 MB

  gn_kernel<<<dim3(64), dim3(256), 0, stream>>>(xA, xB, gwA, gbA, gwB, gbB, xn, xnT);
  qkv_kernel<<<dim3(NSB * 24 * 64), dim3(256), 0, stream>>>(wqA, wqB, xnT, qT, kT, vv);
  flash_kernel<<<dim3(1024), dim3(256), 0, stream>>>(qT, kT, vv, ao);
  outproj_kernel<<<dim3(NSB * 8 * 64), dim3(256), 0, stream>>>(woA, boA, woB, boB, ao, xn, out);
}

// Round 10
// 429.105 us; speedup vs baseline: 1.0190x; 1.0190x over previous
//
#include <hip/hip_runtime.h>
#include <hip/hip_bf16.h>

typedef __attribute__((ext_vector_type(8))) short short8;
typedef __attribute__((ext_vector_type(4))) short s16x4;
typedef __attribute__((ext_vector_type(4))) float f32x4;
typedef __attribute__((ext_vector_type(4))) float float4v;

#define L 4096
#define CCH 128
#define NH 4
#define HD 32
#define NSB 4  // 2 streams * 2 batches
#define WQ_ELEMS 49152   // 3C*C per stream
#define WO_ELEMS 16384   // C*C per stream

static __device__ __forceinline__ unsigned short f2bf(float f) {
  unsigned int u = __float_as_uint(f);
  u += 0x7FFFu + ((u >> 16) & 1u);
  return (unsigned short)(u >> 16);
}

#if __has_builtin(__builtin_amdgcn_mfma_f32_16x16x16bf16_1k)
static __device__ __forceinline__ f32x4 mfma16(s16x4 a, s16x4 b, f32x4 c) {
  return __builtin_amdgcn_mfma_f32_16x16x16bf16_1k(a, b, c, 0, 0, 0);
}
#else
static __device__ __forceinline__ f32x4 mfma16(s16x4 a, s16x4 b, f32x4 c) {
  asm volatile("v_mfma_f32_16x16x16_bf16 %0, %1, %2, %0"
               : "+v"(c) : "v"(a), "v"(b));
  return c;
}
#endif

// ---------------- Weight pre-convert: 128 blocks, f32 -> bf16 once ---------------
__global__ void __launch_bounds__(256) wconv_kernel(
    const float* __restrict__ wqA, const float* __restrict__ wqB,
    const float* __restrict__ woA, const float* __restrict__ woB,
    unsigned short* __restrict__ wq, unsigned short* __restrict__ wo) {
  int i = (blockIdx.x * 256 + threadIdx.x) * 4;
  const float* src;
  unsigned short* dst;
  if (i < WQ_ELEMS)            { src = wqA + i;                     dst = wq + i; }
  else if (i < 2 * WQ_ELEMS)   { src = wqB + (i - WQ_ELEMS);        dst = wq + i; }
  else if (i < 2 * WQ_ELEMS + WO_ELEMS)
                               { src = woA + (i - 2 * WQ_ELEMS);    dst = wo + (i - 2 * WQ_ELEMS); }
  else                         { src = woB + (i - 2 * WQ_ELEMS - WO_ELEMS);
                                 dst = wo + (i - 2 * WQ_ELEMS); }
  float4v v = *(const float4v*)src;
  s16x4 o;
  #pragma unroll
  for (int j = 0; j < 4; ++j) o[j] = (short)f2bf(v[j]);
  *(s16x4*)dst = o;
}

// ---------------- GN stats: 64 blocks (s*32 + b*16 + g), 256 thr -----------------
__global__ void __launch_bounds__(256) gn_stats_kernel(
    const float* __restrict__ xA, const float* __restrict__ xB,
    float* __restrict__ stats) {
  int bid = blockIdx.x;
  int g = bid & 15;
  int b = (bid >> 4) & 1;
  int s = bid >> 5;
  const float* x = s ? xB : xA;
  const float* xb = x + (size_t)b * CCH * L + (size_t)g * 8 * L;
  int t = threadIdx.x;
  float sum = 0.f, sq = 0.f;
  for (int e = t * 4; e < 8 * L; e += 1024) {
    float4v v = *(const float4v*)(xb + e);
    #pragma unroll
    for (int j = 0; j < 4; ++j) { sum += v[j]; sq += v[j] * v[j]; }
  }
  #pragma unroll
  for (int off = 32; off; off >>= 1) {
    sum += __shfl_down(sum, off);
    sq  += __shfl_down(sq, off);
  }
  __shared__ float red[2][4];
  int w = t >> 6, lane = t & 63;
  if (lane == 0) { red[0][w] = sum; red[1][w] = sq; }
  __syncthreads();
  if (t == 0) {
    float S = red[0][0] + red[0][1] + red[0][2] + red[0][3];
    float Q = red[1][0] + red[1][1] + red[1][2] + red[1][3];
    float mu = S * (1.f / 32768.f);
    float var = Q * (1.f / 32768.f) - mu * mu;
    stats[bid * 2] = mu;
    stats[bid * 2 + 1] = rsqrtf(var + 1e-5f);
  }
}

// ---------------- GN apply: 1024 blocks, 256 thr, 8 elem/thread ------------------
__global__ void __launch_bounds__(256) gn_apply_kernel(
    const float* __restrict__ xA, const float* __restrict__ xB,
    const float* __restrict__ gwA, const float* __restrict__ gbA,
    const float* __restrict__ gwB, const float* __restrict__ gbB,
    const float* __restrict__ stats,
    float* __restrict__ xn, unsigned short* __restrict__ xnT) {
  int i = (blockIdx.x * 256 + threadIdx.x) * 8;  // flat over [sb][c][l]
  int l = i & (L - 1);
  int c = (i >> 12) & 127;
  int sb = i >> 19;
  int s = sb >> 1, b = sb & 1, g = c >> 3;
  const float* x  = s ? xB : xA;
  const float* gw = s ? gwB : gwA;
  const float* gb = s ? gbB : gbA;
  float mu = stats[(sb * 16 + g) * 2];
  float rs = stats[(sb * 16 + g) * 2 + 1];
  float sc = rs * gw[c];
  float bi = gb[c] - mu * sc;
  const float* xp = x + (size_t)b * CCH * L + (size_t)c * L + l;
  float4v v0 = *(const float4v*)(xp);
  float4v v1 = *(const float4v*)(xp + 4);
  float r[8];
  #pragma unroll
  for (int j = 0; j < 4; ++j) { r[j] = v0[j] * sc + bi; r[4 + j] = v1[j] * sc + bi; }
  float* xo = xn + ((size_t)sb * CCH + c) * L + l;
  *(float4v*)(xo) = *(const float4v*)(r);
  *(float4v*)(xo + 4) = *(const float4v*)(r + 4);
  unsigned short* xt = xnT + ((size_t)sb * L + l) * CCH + c;
  #pragma unroll
  for (int j = 0; j < 8; ++j) xt[(size_t)j * CCH] = f2bf(r[j]);
}

// ---------------- QKV GEMM: grid NSB*24*64, 256 thr (4 waves, one 16x16 tile each) --
// y[o][l] = sum_c w[o][c] * xn[c][l];  o in [0,384), per (s,b).
// Weights pre-converted to bf16 (wconv) => A-frag is a contiguous short8 load.
// Writes qT/kT as [sb][h][L][32] bf16, v as [sb][h][32][L] bf16.
// q is PRE-SCALED by 1/sqrt(128) here so flash skips the per-score scale.
__global__ void __launch_bounds__(256) qkv_kernel(
    const unsigned short* __restrict__ wqbf,
    const unsigned short* __restrict__ xnT,
    unsigned short* __restrict__ qT, unsigned short* __restrict__ kT,
    unsigned short* __restrict__ vv) {
  int bid = blockIdx.x;
  int nc = bid & 63;
  int mt = (bid >> 6) % 24;
  int sb = bid / (24 * 64);
  int s = sb >> 1;
  const unsigned short* wq = wqbf + (size_t)s * WQ_ELEMS;
  int t = threadIdx.x;
  int w = t >> 6, lane = t & 63, ln = lane & 15, sub = lane >> 4;
  int obase = mt * 16;
  int lbase = nc * 64 + w * 16;
  const unsigned short* bbase = xnT + ((size_t)sb * L + lbase + ln) * CCH;
  const unsigned short* abase = wq + (size_t)(obase + ln) * CCH;
  f32x4 acc = {0.f, 0.f, 0.f, 0.f};
  #pragma unroll
  for (int kc = 0; kc < 4; ++kc) {
    int k0 = kc * 32 + sub * 8;
    short8 af = *(const short8*)(abase + k0);
    short8 bfr = *(const short8*)(bbase + k0);
    acc = __builtin_amdgcn_mfma_f32_16x16x32_bf16(af, bfr, acc, 0, 0, 0);
  }
  const float qscale = 0.08838834764831845f;  // 1/sqrt(128)
  int lcol = lbase + ln;
  #pragma unroll
  for (int r = 0; r < 4; ++r) {
    int o = obase + sub * 4 + r;
    int head = o / 96;
    int rem = o - head * 96;
    int part = rem >> 5;
    int dd = rem & 31;
    size_t bh = (size_t)sb * NH + head;
    if (part == 0)      qT[(bh * L + lcol) * HD + dd] = f2bf(acc[r] * qscale);
    else if (part == 1) kT[(bh * L + lcol) * HD + dd] = f2bf(acc[r]);
    else                vv[(bh * HD + dd) * L + lcol] = f2bf(acc[r]);
  }
}

// ---------------- Flash attention: grid 2*2*4*64 = 1024 blocks, 256 thr -------------
// Output stream s uses queries of stream s^1 and K/V of stream s.
// Swapped-operand S: S^T = mfma(K-frag, Q-frag) -> C[m=k][n=q]; each lane owns one
// q-column (q=ln), k spread across sub groups => softmax reduce = 15 local ops + 2
// shuffles. P^T lane layout (k = sub*4+r) IS the B-frag of the K=16 bf16 MFMA, so
// PV: O^T += mfma16(V^T-frag, P^T) with zero cross-lane movement and no LDS.
__global__ void __launch_bounds__(256) flash_kernel(
    const unsigned short* __restrict__ qT, const unsigned short* __restrict__ kT,
    const unsigned short* __restrict__ vv, unsigned short* __restrict__ ao) {
  int bid = blockIdx.x;
  int qt = bid & 63;
  int h  = (bid >> 6) & 3;
  int b  = (bid >> 8) & 1;
  int s  = bid >> 9;
  size_t bh_kv = (size_t)((s * 2 + b) * NH + h);
  size_t bh_q  = (size_t)(((s ^ 1) * 2 + b) * NH + h);
  const unsigned short* qTb = qT + bh_q * L * HD;
  const unsigned short* kTb = kT + bh_kv * L * HD;
  const unsigned short* vb  = vv + bh_kv * HD * L;

  int t = threadIdx.x;
  int w = t >> 6, lane = t & 63, ln = lane & 15, sub = lane >> 4;
  int qbase = qt * 64 + w * 16;

  // Q B-frag, hoisted: B[kk=d][n=q] = qT[qbase+ln][sub*8 + j] (pre-scaled)
  short8 bq = *(const short8*)(qTb + (size_t)(qbase + ln) * HD + sub * 8);

  f32x4 acc0 = {0.f, 0.f, 0.f, 0.f};  // O^T[d=sub*4+r   ][q=ln]
  f32x4 acc1 = {0.f, 0.f, 0.f, 0.f};  // O^T[d=16+sub*4+r][q=ln]
  float m = -1e30f, lsum = 0.f;

  for (int kt = 0; kt < L / 64; ++kt) {
    int kbase = kt * 64;
    // S^T for 4 k-tiles of 16: sc_tt[r] = S[k=kbase+16*tt+sub*4+r][q=ln]
    f32x4 sc0, sc1, sc2, sc3;
    {
      f32x4 zz = {0.f, 0.f, 0.f, 0.f};
      short8 ak0 = *(const short8*)(kTb + (size_t)(kbase +  0 + ln) * HD + sub * 8);
      short8 ak1 = *(const short8*)(kTb + (size_t)(kbase + 16 + ln) * HD + sub * 8);
      short8 ak2 = *(const short8*)(kTb + (size_t)(kbase + 32 + ln) * HD + sub * 8);
      short8 ak3 = *(const short8*)(kTb + (size_t)(kbase + 48 + ln) * HD + sub * 8);
      sc0 = __builtin_amdgcn_mfma_f32_16x16x32_bf16(ak0, bq, zz, 0, 0, 0);
      sc1 = __builtin_amdgcn_mfma_f32_16x16x32_bf16(ak1, bq, zz, 0, 0, 0);
      sc2 = __builtin_amdgcn_mfma_f32_16x16x32_bf16(ak2, bq, zz, 0, 0, 0);
      sc3 = __builtin_amdgcn_mfma_f32_16x16x32_bf16(ak3, bq, zz, 0, 0, 0);
    }
    // online softmax over the lane's 16 scores + 2 cross-lane shuffles
    float mx = sc0[0];
    #pragma unroll
    for (int r = 0; r < 4; ++r) {
      mx = fmaxf(mx, sc0[r]); mx = fmaxf(mx, sc1[r]);
      mx = fmaxf(mx, sc2[r]); mx = fmaxf(mx, sc3[r]);
    }
    mx = fmaxf(mx, __shfl_xor(mx, 16));
    mx = fmaxf(mx, __shfl_xor(mx, 32));
    float newm = fmaxf(m, mx);
    float alpha = __expf(m - newm);
    float rsum = 0.f;
    s16x4 bp0, bp1, bp2, bp3;
    #pragma unroll
    for (int r = 0; r < 4; ++r) {
      float p0 = __expf(sc0[r] - newm);
      float p1 = __expf(sc1[r] - newm);
      float p2 = __expf(sc2[r] - newm);
      float p3 = __expf(sc3[r] - newm);
      rsum += (p0 + p1) + (p2 + p3);
      bp0[r] = (short)f2bf(p0);
      bp1[r] = (short)f2bf(p1);
      bp2[r] = (short)f2bf(p2);
      bp3[r] = (short)f2bf(p3);
    }
    rsum += __shfl_xor(rsum, 16);
    rsum += __shfl_xor(rsum, 32);
    lsum = lsum * alpha + rsum;
    m = newm;
    #pragma unroll
    for (int r = 0; r < 4; ++r) { acc0[r] *= alpha; acc1[r] *= alpha; }
    // PV: A-frag V^T: A[m=d][kk=k] = vv[d][kbase+16*tt+sub*4+j] (contig s16x4)
    #pragma unroll
    for (int tt = 0; tt < 4; ++tt) {
      s16x4 bp = (tt == 0) ? bp0 : (tt == 1) ? bp1 : (tt == 2) ? bp2 : bp3;
      int koff = kbase + 16 * tt + sub * 4;
      s16x4 av0 = *(const s16x4*)(vb + (size_t)ln * L + koff);
      s16x4 av1 = *(const s16x4*)(vb + (size_t)(16 + ln) * L + koff);
      acc0 = mfma16(av0, bp, acc0);
      acc1 = mfma16(av1, bp, acc1);
    }
  }

  // epilogue: normalize, write attn_out as [sb][L][C] bf16 (c = h*32 + d)
  float inv = 1.0f / lsum;
  int qrow = qbase + ln;
  size_t rowoff = ((size_t)(s * 2 + b) * L + qrow) * CCH + h * HD;
  s16x4 o0, o1;
  #pragma unroll
  for (int r = 0; r < 4; ++r) {
    o0[r] = (short)f2bf(acc0[r] * inv);
    o1[r] = (short)f2bf(acc1[r] * inv);
  }
  *(s16x4*)(ao + rowoff + sub * 4) = o0;
  *(s16x4*)(ao + rowoff + 16 + sub * 4) = o1;
}

// ---------------- Out-proj GEMM + bias + residual: grid NSB*8*64, 256 thr -----------
__global__ void __launch_bounds__(256) outproj_kernel(
    const unsigned short* __restrict__ wobf,
    const float* __restrict__ boA, const float* __restrict__ boB,
    const unsigned short* __restrict__ ao, const float* __restrict__ xn,
    float* __restrict__ out) {
  int bid = blockIdx.x;
  int nc = bid & 63;
  int mt = (bid >> 6) & 7;
  int sb = bid >> 9;
  int s = sb >> 1;
  int b = sb & 1;
  const unsigned short* wo = wobf + (size_t)s * WO_ELEMS;
  const float* bo = s ? boB : boA;
  int t = threadIdx.x;
  int w = t >> 6, lane = t & 63, ln = lane & 15, sub = lane >> 4;
  int obase = mt * 16;
  int lbase = nc * 64 + w * 16;
  const unsigned short* bbase = ao + ((size_t)sb * L + lbase + ln) * CCH;
  const unsigned short* abase = wo + (size_t)(obase + ln) * CCH;
  f32x4 acc = {0.f, 0.f, 0.f, 0.f};
  #pragma unroll
  for (int kc = 0; kc < 4; ++kc) {
    int k0 = kc * 32 + sub * 8;
    short8 af = *(const short8*)(abase + k0);
    short8 bfr = *(const short8*)(bbase + k0);
    acc = __builtin_amdgcn_mfma_f32_16x16x32_bf16(af, bfr, acc, 0, 0, 0);
  }
  int lcol = lbase + ln;
  #pragma unroll
  for (int r = 0; r < 4; ++r) {
    int o = obase + sub * 4 + r;
    out[(size_t)s * (2 * CCH * L) + ((size_t)b * CCH + o) * L + lcol] =
        acc[r] + bo[o] + xn[((size_t)sb * CCH + o) * L + lcol];
  }
}

extern "C" void kernel_launch(void* const* d_in, const int* in_sizes, int n_in,
                              void* d_out, int out_size, void* d_ws, size_t ws_size,
                              hipStream_t stream) {
  (void)in_sizes; (void)n_in; (void)out_size; (void)ws_size;
  const float* xA  = (const float*)d_in[0];
  const float* xB  = (const float*)d_in[1];
  const float* gwA = (const float*)d_in[2];
  const float* gbA = (const float*)d_in[3];
  const float* gwB = (const float*)d_in[4];
  const float* gbB = (const float*)d_in[5];
  const float* wqA = (const float*)d_in[6];
  const float* wqB = (const float*)d_in[7];
  const float* woA = (const float*)d_in[8];
  const float* boA = (const float*)d_in[9];
  const float* woB = (const float*)d_in[10];
  const float* boB = (const float*)d_in[11];
  float* out = (float*)d_out;

  char* ws = (char*)d_ws;
  size_t off = 0;
  float* xn = (float*)(ws + off);            off += (size_t)NSB * CCH * L * sizeof(float); // 8 MB
  unsigned short* xnT = (unsigned short*)(ws + off); off += (size_t)NSB * L * CCH * 2;     // 4 MB
  unsigned short* qT  = (unsigned short*)(ws + off); off += (size_t)NSB * NH * L * HD * 2; // 4 MB
  unsigned short* kT  = (unsigned short*)(ws + off); off += (size_t)NSB * NH * L * HD * 2; // 4 MB
  unsigned short* vv  = (unsigned short*)(ws + off); off += (size_t)NSB * NH * HD * L * 2; // 4 MB
  unsigned short* ao  = (unsigned short*)(ws + off); off += (size_t)NSB * L * CCH * 2;     // 4 MB
  float* stats = (float*)(ws + off);         off += 64 * 2 * sizeof(float);
  unsigned short* wqbf = (unsigned short*)(ws + off); off += (size_t)2 * WQ_ELEMS * 2;     // 192 KB
  unsigned short* wobf = (unsigned short*)(ws + off); off += (size_t)2 * WO_ELEMS * 2;     // 64 KB

  wconv_kernel<<<dim3(128), dim3(256), 0, stream>>>(wqA, wqB, woA, woB, wqbf, wobf);
  gn_stats_kernel<<<dim3(64), dim3(256), 0, stream>>>(xA, xB, stats);
  gn_apply_kernel<<<dim3(1024), dim3(256), 0, stream>>>(xA, xB, gwA, gbA, gwB, gbB,
                                                        stats, xn, xnT);
  qkv_kernel<<<dim3(NSB * 24 * 64), dim3(256), 0, stream>>>(wqbf, xnT, qT, kT, vv);
  flash_kernel<<<dim3(1024), dim3(256), 0, stream>>>(qT, kT, vv, ao);
  outproj_kernel<<<dim3(NSB * 8 * 64), dim3(256), 0, stream>>>(wobf, boA, boB, ao, xn, out);
}

// Round 11
// 287.655 us; speedup vs baseline: 1.5200x; 1.4917x over previous
//
#include <hip/hip_runtime.h>
#include <hip/hip_bf16.h>

typedef __attribute__((ext_vector_type(8))) short short8;
typedef __attribute__((ext_vector_type(4))) short s16x4;
typedef __attribute__((ext_vector_type(4))) float f32x4;
typedef __attribute__((ext_vector_type(4))) float float4v;

#define L 4096
#define CCH 128
#define NH 4
#define HD 32
#define NSB 4  // 2 streams * 2 batches
#define WQ_ELEMS 49152   // 3C*C per stream
#define WO_ELEMS 16384   // C*C per stream

static __device__ __forceinline__ unsigned short f2bf(float f) {
  unsigned int u = __float_as_uint(f);
  u += 0x7FFFu + ((u >> 16) & 1u);
  return (unsigned short)(u >> 16);
}

#if __has_builtin(__builtin_amdgcn_mfma_f32_16x16x16bf16_1k)
static __device__ __forceinline__ f32x4 mfma16(s16x4 a, s16x4 b, f32x4 c) {
  return __builtin_amdgcn_mfma_f32_16x16x16bf16_1k(a, b, c, 0, 0, 0);
}
#else
static __device__ __forceinline__ f32x4 mfma16(s16x4 a, s16x4 b, f32x4 c) {
  // non-volatile: pure computation, let the scheduler move it freely
  asm("v_mfma_f32_16x16x16_bf16 %0, %1, %2, %0"
      : "+v"(c) : "v"(a), "v"(b));
  return c;
}
#endif

// ---------------- Weight pre-convert: 128 blocks, f32 -> bf16 once ---------------
__global__ void __launch_bounds__(256) wconv_kernel(
    const float* __restrict__ wqA, const float* __restrict__ wqB,
    const float* __restrict__ woA, const float* __restrict__ woB,
    unsigned short* __restrict__ wq, unsigned short* __restrict__ wo) {
  int i = (blockIdx.x * 256 + threadIdx.x) * 4;
  const float* src;
  unsigned short* dst;
  if (i < WQ_ELEMS)            { src = wqA + i;                     dst = wq + i; }
  else if (i < 2 * WQ_ELEMS)   { src = wqB + (i - WQ_ELEMS);        dst = wq + i; }
  else if (i < 2 * WQ_ELEMS + WO_ELEMS)
                               { src = woA + (i - 2 * WQ_ELEMS);    dst = wo + (i - 2 * WQ_ELEMS); }
  else                         { src = woB + (i - 2 * WQ_ELEMS - WO_ELEMS);
                                 dst = wo + (i - 2 * WQ_ELEMS); }
  float4v v = *(const float4v*)src;
  s16x4 o;
  #pragma unroll
  for (int j = 0; j < 4; ++j) o[j] = (short)f2bf(v[j]);
  *(s16x4*)dst = o;
}

// ---------------- GN stats: 64 blocks (s*32 + b*16 + g), 256 thr -----------------
__global__ void __launch_bounds__(256) gn_stats_kernel(
    const float* __restrict__ xA, const float* __restrict__ xB,
    float* __restrict__ stats) {
  int bid = blockIdx.x;
  int g = bid & 15;
  int b = (bid >> 4) & 1;
  int s = bid >> 5;
  const float* x = s ? xB : xA;
  const float* xb = x + (size_t)b * CCH * L + (size_t)g * 8 * L;
  int t = threadIdx.x;
  float sum = 0.f, sq = 0.f;
  for (int e = t * 4; e < 8 * L; e += 1024) {
    float4v v = *(const float4v*)(xb + e);
    #pragma unroll
    for (int j = 0; j < 4; ++j) { sum += v[j]; sq += v[j] * v[j]; }
  }
  #pragma unroll
  for (int off = 32; off; off >>= 1) {
    sum += __shfl_down(sum, off);
    sq  += __shfl_down(sq, off);
  }
  __shared__ float red[2][4];
  int w = t >> 6, lane = t & 63;
  if (lane == 0) { red[0][w] = sum; red[1][w] = sq; }
  __syncthreads();
  if (t == 0) {
    float S = red[0][0] + red[0][1] + red[0][2] + red[0][3];
    float Q = red[1][0] + red[1][1] + red[1][2] + red[1][3];
    float mu = S * (1.f / 32768.f);
    float var = Q * (1.f / 32768.f) - mu * mu;
    stats[bid * 2] = mu;
    stats[bid * 2 + 1] = rsqrtf(var + 1e-5f);
  }
}

// ---------------- GN apply: 1024 blocks, 256 thr, 8 elem/thread ------------------
__global__ void __launch_bounds__(256) gn_apply_kernel(
    const float* __restrict__ xA, const float* __restrict__ xB,
    const float* __restrict__ gwA, const float* __restrict__ gbA,
    const float* __restrict__ gwB, const float* __restrict__ gbB,
    const float* __restrict__ stats,
    float* __restrict__ xn, unsigned short* __restrict__ xnT) {
  int i = (blockIdx.x * 256 + threadIdx.x) * 8;  // flat over [sb][c][l]
  int l = i & (L - 1);
  int c = (i >> 12) & 127;
  int sb = i >> 19;
  int s = sb >> 1, b = sb & 1, g = c >> 3;
  const float* x  = s ? xB : xA;
  const float* gw = s ? gwB : gwA;
  const float* gb = s ? gbB : gbA;
  float mu = stats[(sb * 16 + g) * 2];
  float rs = stats[(sb * 16 + g) * 2 + 1];
  float sc = rs * gw[c];
  float bi = gb[c] - mu * sc;
  const float* xp = x + (size_t)b * CCH * L + (size_t)c * L + l;
  float4v v0 = *(const float4v*)(xp);
  float4v v1 = *(const float4v*)(xp + 4);
  float r[8];
  #pragma unroll
  for (int j = 0; j < 4; ++j) { r[j] = v0[j] * sc + bi; r[4 + j] = v1[j] * sc + bi; }
  float* xo = xn + ((size_t)sb * CCH + c) * L + l;
  *(float4v*)(xo) = *(const float4v*)(r);
  *(float4v*)(xo + 4) = *(const float4v*)(r + 4);
  unsigned short* xt = xnT + ((size_t)sb * L + l) * CCH + c;
  #pragma unroll
  for (int j = 0; j < 8; ++j) xt[(size_t)j * CCH] = f2bf(r[j]);
}

// ---------------- QKV GEMM: grid NSB*24*64, 256 thr (4 waves, one 16x16 tile each) --
__global__ void __launch_bounds__(256, 4) qkv_kernel(
    const unsigned short* __restrict__ wqbf,
    const unsigned short* __restrict__ xnT,
    unsigned short* __restrict__ qT, unsigned short* __restrict__ kT,
    unsigned short* __restrict__ vv) {
  int bid = blockIdx.x;
  int nc = bid & 63;
  int mt = (bid >> 6) % 24;
  int sb = bid / (24 * 64);
  int s = sb >> 1;
  const unsigned short* wq = wqbf + (size_t)s * WQ_ELEMS;
  int t = threadIdx.x;
  int w = t >> 6, lane = t & 63, ln = lane & 15, sub = lane >> 4;
  int obase = mt * 16;
  int lbase = nc * 64 + w * 16;
  const unsigned short* bbase = xnT + ((size_t)sb * L + lbase + ln) * CCH;
  const unsigned short* abase = wq + (size_t)(obase + ln) * CCH;
  f32x4 acc = {0.f, 0.f, 0.f, 0.f};
  #pragma unroll
  for (int kc = 0; kc < 4; ++kc) {
    int k0 = kc * 32 + sub * 8;
    short8 af = *(const short8*)(abase + k0);
    short8 bfr = *(const short8*)(bbase + k0);
    acc = __builtin_amdgcn_mfma_f32_16x16x32_bf16(af, bfr, acc, 0, 0, 0);
  }
  const float qscale = 0.08838834764831845f;  // 1/sqrt(128)
  int lcol = lbase + ln;
  #pragma unroll
  for (int r = 0; r < 4; ++r) {
    int o = obase + sub * 4 + r;
    int head = o / 96;
    int rem = o - head * 96;
    int part = rem >> 5;
    int dd = rem & 31;
    size_t bh = (size_t)sb * NH + head;
    if (part == 0)      qT[(bh * L + lcol) * HD + dd] = f2bf(acc[r] * qscale);
    else if (part == 1) kT[(bh * L + lcol) * HD + dd] = f2bf(acc[r]);
    else                vv[(bh * HD + dd) * L + lcol] = f2bf(acc[r]);
  }
}

// ---------------- Flash attention: grid 2*2*4*32 = 512 blocks, 256 thr --------------
// Each wave owns 32 q-rows (2 independent 16-q chains) sharing the K/V loads:
// halves cache traffic, doubles per-wave ILP. __launch_bounds__(256,2) gives the
// register allocator headroom (grid is 2 blocks/CU) so loads stay in flight.
__global__ void __launch_bounds__(256, 2) flash_kernel(
    const unsigned short* __restrict__ qT, const unsigned short* __restrict__ kT,
    const unsigned short* __restrict__ vv, unsigned short* __restrict__ ao) {
  int bid = blockIdx.x;
  int qt = bid & 31;
  int h  = (bid >> 5) & 3;
  int b  = (bid >> 7) & 1;
  int s  = bid >> 8;
  size_t bh_kv = (size_t)((s * 2 + b) * NH + h);
  size_t bh_q  = (size_t)(((s ^ 1) * 2 + b) * NH + h);
  const unsigned short* qTb = qT + bh_q * L * HD;
  const unsigned short* kTb = kT + bh_kv * L * HD;
  const unsigned short* vb  = vv + bh_kv * HD * L;

  int t = threadIdx.x;
  int w = t >> 6, lane = t & 63, ln = lane & 15, sub = lane >> 4;
  int qbase = qt * 128 + w * 32;

  // Q B-frags for the two chains (pre-scaled by 1/sqrt(128) in qkv)
  short8 bq0 = *(const short8*)(qTb + (size_t)(qbase + ln) * HD + sub * 8);
  short8 bq1 = *(const short8*)(qTb + (size_t)(qbase + 16 + ln) * HD + sub * 8);

  f32x4 acc00 = {0.f, 0.f, 0.f, 0.f}, acc01 = {0.f, 0.f, 0.f, 0.f};
  f32x4 acc10 = {0.f, 0.f, 0.f, 0.f}, acc11 = {0.f, 0.f, 0.f, 0.f};
  float m0 = -1e30f, l0 = 0.f;
  float m1 = -1e30f, l1 = 0.f;

  for (int kt = 0; kt < L / 64; ++kt) {
    int kbase = kt * 64;
    // K A-frags (shared by both chains): rows kbase+16*tt+ln, cols sub*8..+8
    short8 ak0 = *(const short8*)(kTb + (size_t)(kbase +  0 + ln) * HD + sub * 8);
    short8 ak1 = *(const short8*)(kTb + (size_t)(kbase + 16 + ln) * HD + sub * 8);
    short8 ak2 = *(const short8*)(kTb + (size_t)(kbase + 32 + ln) * HD + sub * 8);
    short8 ak3 = *(const short8*)(kTb + (size_t)(kbase + 48 + ln) * HD + sub * 8);
    // V A-frags (shared): av{tt}{half}: d = half*16+ln, k = kbase+16*tt+sub*4..+4
    s16x4 av00 = *(const s16x4*)(vb + (size_t)ln * L + kbase +  0 + sub * 4);
    s16x4 av01 = *(const s16x4*)(vb + (size_t)(16 + ln) * L + kbase +  0 + sub * 4);
    s16x4 av10 = *(const s16x4*)(vb + (size_t)ln * L + kbase + 16 + sub * 4);
    s16x4 av11 = *(const s16x4*)(vb + (size_t)(16 + ln) * L + kbase + 16 + sub * 4);
    s16x4 av20 = *(const s16x4*)(vb + (size_t)ln * L + kbase + 32 + sub * 4);
    s16x4 av21 = *(const s16x4*)(vb + (size_t)(16 + ln) * L + kbase + 32 + sub * 4);
    s16x4 av30 = *(const s16x4*)(vb + (size_t)ln * L + kbase + 48 + sub * 4);
    s16x4 av31 = *(const s16x4*)(vb + (size_t)(16 + ln) * L + kbase + 48 + sub * 4);

    f32x4 zz = {0.f, 0.f, 0.f, 0.f};
    // S^T both chains: sX_tt[r] = S[k=kbase+16*tt+sub*4+r][q-chain col ln]
    f32x4 sa0 = __builtin_amdgcn_mfma_f32_16x16x32_bf16(ak0, bq0, zz, 0, 0, 0);
    f32x4 sa1 = __builtin_amdgcn_mfma_f32_16x16x32_bf16(ak1, bq0, zz, 0, 0, 0);
    f32x4 sa2 = __builtin_amdgcn_mfma_f32_16x16x32_bf16(ak2, bq0, zz, 0, 0, 0);
    f32x4 sa3 = __builtin_amdgcn_mfma_f32_16x16x32_bf16(ak3, bq0, zz, 0, 0, 0);
    f32x4 sb0 = __builtin_amdgcn_mfma_f32_16x16x32_bf16(ak0, bq1, zz, 0, 0, 0);
    f32x4 sb1 = __builtin_amdgcn_mfma_f32_16x16x32_bf16(ak1, bq1, zz, 0, 0, 0);
    f32x4 sb2 = __builtin_amdgcn_mfma_f32_16x16x32_bf16(ak2, bq1, zz, 0, 0, 0);
    f32x4 sb3 = __builtin_amdgcn_mfma_f32_16x16x32_bf16(ak3, bq1, zz, 0, 0, 0);

    // ---- softmax chain 0 ----
    s16x4 bp00, bp01, bp02, bp03;
    {
      float mx = fmaxf(fmaxf(sa0[0], sa0[1]), fmaxf(sa0[2], sa0[3]));
      mx = fmaxf(mx, fmaxf(fmaxf(sa1[0], sa1[1]), fmaxf(sa1[2], sa1[3])));
      mx = fmaxf(mx, fmaxf(fmaxf(sa2[0], sa2[1]), fmaxf(sa2[2], sa2[3])));
      mx = fmaxf(mx, fmaxf(fmaxf(sa3[0], sa3[1]), fmaxf(sa3[2], sa3[3])));
      mx = fmaxf(mx, __shfl_xor(mx, 16));
      mx = fmaxf(mx, __shfl_xor(mx, 32));
      float newm = fmaxf(m0, mx);
      float alpha = __expf(m0 - newm);
      float rsum = 0.f;
      #pragma unroll
      for (int r = 0; r < 4; ++r) {
        float p0 = __expf(sa0[r] - newm);
        float p1 = __expf(sa1[r] - newm);
        float p2 = __expf(sa2[r] - newm);
        float p3 = __expf(sa3[r] - newm);
        rsum += (p0 + p1) + (p2 + p3);
        bp00[r] = (short)f2bf(p0);
        bp01[r] = (short)f2bf(p1);
        bp02[r] = (short)f2bf(p2);
        bp03[r] = (short)f2bf(p3);
      }
      rsum += __shfl_xor(rsum, 16);
      rsum += __shfl_xor(rsum, 32);
      l0 = l0 * alpha + rsum;
      m0 = newm;
      #pragma unroll
      for (int r = 0; r < 4; ++r) { acc00[r] *= alpha; acc01[r] *= alpha; }
    }
    // ---- softmax chain 1 ----
    s16x4 bp10, bp11, bp12, bp13;
    {
      float mx = fmaxf(fmaxf(sb0[0], sb0[1]), fmaxf(sb0[2], sb0[3]));
      mx = fmaxf(mx, fmaxf(fmaxf(sb1[0], sb1[1]), fmaxf(sb1[2], sb1[3])));
      mx = fmaxf(mx, fmaxf(fmaxf(sb2[0], sb2[1]), fmaxf(sb2[2], sb2[3])));
      mx = fmaxf(mx, fmaxf(fmaxf(sb3[0], sb3[1]), fmaxf(sb3[2], sb3[3])));
      mx = fmaxf(mx, __shfl_xor(mx, 16));
      mx = fmaxf(mx, __shfl_xor(mx, 32));
      float newm = fmaxf(m1, mx);
      float alpha = __expf(m1 - newm);
      float rsum = 0.f;
      #pragma unroll
      for (int r = 0; r < 4; ++r) {
        float p0 = __expf(sb0[r] - newm);
        float p1 = __expf(sb1[r] - newm);
        float p2 = __expf(sb2[r] - newm);
        float p3 = __expf(sb3[r] - newm);
        rsum += (p0 + p1) + (p2 + p3);
        bp10[r] = (short)f2bf(p0);
        bp11[r] = (short)f2bf(p1);
        bp12[r] = (short)f2bf(p2);
        bp13[r] = (short)f2bf(p3);
      }
      rsum += __shfl_xor(rsum, 16);
      rsum += __shfl_xor(rsum, 32);
      l1 = l1 * alpha + rsum;
      m1 = newm;
      #pragma unroll
      for (int r = 0; r < 4; ++r) { acc10[r] *= alpha; acc11[r] *= alpha; }
    }
    // ---- PV both chains (V frags shared) ----
    acc00 = mfma16(av00, bp00, acc00); acc01 = mfma16(av01, bp00, acc01);
    acc00 = mfma16(av10, bp01, acc00); acc01 = mfma16(av11, bp01, acc01);
    acc00 = mfma16(av20, bp02, acc00); acc01 = mfma16(av21, bp02, acc01);
    acc00 = mfma16(av30, bp03, acc00); acc01 = mfma16(av31, bp03, acc01);
    acc10 = mfma16(av00, bp10, acc10); acc11 = mfma16(av01, bp10, acc11);
    acc10 = mfma16(av10, bp11, acc10); acc11 = mfma16(av11, bp11, acc11);
    acc10 = mfma16(av20, bp12, acc10); acc11 = mfma16(av21, bp12, acc11);
    acc10 = mfma16(av30, bp13, acc10); acc11 = mfma16(av31, bp13, acc11);
  }

  // epilogue: normalize, write attn_out as [sb][L][C] bf16 (c = h*32 + d)
  {
    float inv = 1.0f / l0;
    int qrow = qbase + ln;
    size_t rowoff = ((size_t)(s * 2 + b) * L + qrow) * CCH + h * HD;
    s16x4 o0, o1;
    #pragma unroll
    for (int r = 0; r < 4; ++r) {
      o0[r] = (short)f2bf(acc00[r] * inv);
      o1[r] = (short)f2bf(acc01[r] * inv);
    }
    *(s16x4*)(ao + rowoff + sub * 4) = o0;
    *(s16x4*)(ao + rowoff + 16 + sub * 4) = o1;
  }
  {
    float inv = 1.0f / l1;
    int qrow = qbase + 16 + ln;
    size_t rowoff = ((size_t)(s * 2 + b) * L + qrow) * CCH + h * HD;
    s16x4 o0, o1;
    #pragma unroll
    for (int r = 0; r < 4; ++r) {
      o0[r] = (short)f2bf(acc10[r] * inv);
      o1[r] = (short)f2bf(acc11[r] * inv);
    }
    *(s16x4*)(ao + rowoff + sub * 4) = o0;
    *(s16x4*)(ao + rowoff + 16 + sub * 4) = o1;
  }
}

// ---------------- Out-proj GEMM + bias + residual: grid NSB*8*64, 256 thr -----------
__global__ void __launch_bounds__(256, 4) outproj_kernel(
    const unsigned short* __restrict__ wobf,
    const float* __restrict__ boA, const float* __restrict__ boB,
    const unsigned short* __restrict__ ao, const float* __restrict__ xn,
    float* __restrict__ out) {
  int bid = blockIdx.x;
  int nc = bid & 63;
  int mt = (bid >> 6) & 7;
  int sb = bid >> 9;
  int s = sb >> 1;
  int b = sb & 1;
  const unsigned short* wo = wobf + (size_t)s * WO_ELEMS;
  const float* bo = s ? boB : boA;
  int t = threadIdx.x;
  int w = t >> 6, lane = t & 63, ln = lane & 15, sub = lane >> 4;
  int obase = mt * 16;
  int lbase = nc * 64 + w * 16;
  const unsigned short* bbase = ao + ((size_t)sb * L + lbase + ln) * CCH;
  const unsigned short* abase = wo + (size_t)(obase + ln) * CCH;
  f32x4 acc = {0.f, 0.f, 0.f, 0.f};
  #pragma unroll
  for (int kc = 0; kc < 4; ++kc) {
    int k0 = kc * 32 + sub * 8;
    short8 af = *(const short8*)(abase + k0);
    short8 bfr = *(const short8*)(bbase + k0);
    acc = __builtin_amdgcn_mfma_f32_16x16x32_bf16(af, bfr, acc, 0, 0, 0);
  }
  int lcol = lbase + ln;
  #pragma unroll
  for (int r = 0; r < 4; ++r) {
    int o = obase + sub * 4 + r;
    out[(size_t)s * (2 * CCH * L) + ((size_t)b * CCH + o) * L + lcol] =
        acc[r] + bo[o] + xn[((size_t)sb * CCH + o) * L + lcol];
  }
}

extern "C" void kernel_launch(void* const* d_in, const int* in_sizes, int n_in,
                              void* d_out, int out_size, void* d_ws, size_t ws_size,
                              hipStream_t stream) {
  (void)in_sizes; (void)n_in; (void)out_size; (void)ws_size;
  const float* xA  = (const float*)d_in[0];
  const float* xB  = (const float*)d_in[1];
  const float* gwA = (const float*)d_in[2];
  const float* gbA = (const float*)d_in[3];
  const float* gwB = (const float*)d_in[4];
  const float* gbB = (const float*)d_in[5];
  const float* wqA = (const float*)d_in[6];
  const float* wqB = (const float*)d_in[7];
  const float* woA = (const float*)d_in[8];
  const float* boA = (const float*)d_in[9];
  const float* woB = (const float*)d_in[10];
  const float* boB = (const float*)d_in[11];
  float* out = (float*)d_out;

  char* ws = (char*)d_ws;
  size_t off = 0;
  float* xn = (float*)(ws + off);            off += (size_t)NSB * CCH * L * sizeof(float); // 8 MB
  unsigned short* xnT = (unsigned short*)(ws + off); off += (size_t)NSB * L * CCH * 2;     // 4 MB
  unsigned short* qT  = (unsigned short*)(ws + off); off += (size_t)NSB * NH * L * HD * 2; // 4 MB
  unsigned short* kT  = (unsigned short*)(ws + off); off += (size_t)NSB * NH * L * HD * 2; // 4 MB
  unsigned short* vv  = (unsigned short*)(ws + off); off += (size_t)NSB * NH * HD * L * 2; // 4 MB
  unsigned short* ao  = (unsigned short*)(ws + off); off += (size_t)NSB * L * CCH * 2;     // 4 MB
  float* stats = (float*)(ws + off);         off += 64 * 2 * sizeof(float);
  unsigned short* wqbf = (unsigned short*)(ws + off); off += (size_t)2 * WQ_ELEMS * 2;     // 192 KB
  unsigned short* wobf = (unsigned short*)(ws + off); off += (size_t)2 * WO_ELEMS * 2;     // 64 KB

  wconv_kernel<<<dim3(128), dim3(256), 0, stream>>>(wqA, wqB, woA, woB, wqbf, wobf);
  gn_stats_kernel<<<dim3(64), dim3(256), 0, stream>>>(xA, xB, stats);
  gn_apply_kernel<<<dim3(1024), dim3(256), 0, stream>>>(xA, xB, gwA, gbA, gwB, gbB,
                                                        stats, xn, xnT);
  qkv_kernel<<<dim3(NSB * 24 * 64), dim3(256), 0, stream>>>(wqbf, xnT, qT, kT, vv);
  flash_kernel<<<dim3(512), dim3(256), 0, stream>>>(qT, kT, vv, ao);
  outproj_kernel<<<dim3(NSB * 8 * 64), dim3(256), 0, stream>>>(wobf, boA, boB, ao, xn, out);
}